// Round 8
// baseline (9890.254 us; speedup 1.0000x reference)
//
#include <hip/hip_runtime.h>
#include <math.h>

#define B_ 64
#define T_ 1024
#define I_ 128
#define H_ 512

typedef _Float16 h2_t __attribute__((ext_vector_type(2)));
union U32H2 { unsigned u; h2_t h; };

__device__ __forceinline__ float fdot2u(unsigned a, unsigned b, float c) {
    U32H2 ua, ub; ua.u = a; ub.u = b;
    return __builtin_amdgcn_fdot2(ua.h, ub.h, c, false);
}
__device__ __forceinline__ unsigned packh2(float x, float y) {
    U32H2 r; r.h.x = (_Float16)x; r.h.y = (_Float16)y; return r.u;
}

// ---------------- prep: pack fp16 weights for the 2-WG-per-chain rnn ----------
// rnn map (512 thr/WG, wg half=0/1): w=tid>>6, l=tid&63, c=l&3, u=l>>2,
// g=w*16+u. Thread owns rows (half*256+2g, +1) and k-chunks {c, c+4}
// (chunk j = h2-words 32j..32j+31).
// wpack uint4[half*12288 + slot*512 + tid]:
//   slot 0..15:  r=slot>>3, q=slot&7 -> row half*256+2g+r, words 32c+4q..+3
//   slot 16..23: q=slot-16        -> row half*256+2g,   words 32(c+4)+4q..+3
// wldsg uint4[half*4096 + m*512 + tid]: row half*256+2g+1, words 32(c+4)+4m..+3
// wih2[(i2<<9)+h] = half2 Wih[h][2i2..+1];  biasv[h] = b_ih[h]+b_hh[h]
__global__ void prep(const float* __restrict__ wih, const float* __restrict__ whh,
                     const float* __restrict__ bih, const float* __restrict__ bhh,
                     unsigned* __restrict__ wpack, unsigned* __restrict__ wldsg,
                     unsigned* __restrict__ wih2, float* __restrict__ biasv) {
    int e = blockIdx.x * 256 + threadIdx.x;
    if (e < 98304) {
        int comp = e & 3;
        int u4 = e >> 2;                   // 0..24575
        int half = (u4 >= 12288) ? 1 : 0;
        int rem = u4 - half * 12288;
        int slot = rem >> 9, tid = rem & 511;
        int w = tid >> 6, l = tid & 63, c = l & 3, u = l >> 2;
        int g = w * 16 + u;
        int row, word;
        if (slot < 16) { int r = slot >> 3, q = slot & 7;
            row = half * 256 + 2 * g + r; word = 32 * c + 4 * q + comp; }
        else { int q = slot - 16;
            row = half * 256 + 2 * g;     word = 32 * (c + 4) + 4 * q + comp; }
        wpack[e] = packh2(whh[row * H_ + 2 * word], whh[row * H_ + 2 * word + 1]);
    }
    if (e < 32768) {
        int comp = e & 3;
        int u4 = e >> 2;                   // 0..8191
        int half = u4 >> 12;
        int rem = u4 & 4095;
        int m = rem >> 9, tid = rem & 511;
        int w = tid >> 6, l = tid & 63, c = l & 3, u = l >> 2;
        int g = w * 16 + u;
        int row = half * 256 + 2 * g + 1;
        int word = 32 * (c + 4) + 4 * m + comp;
        wldsg[e] = packh2(whh[row * H_ + 2 * word], whh[row * H_ + 2 * word + 1]);
    }
    if (e < 64 * 512) {
        int i2 = e >> 9, h = e & 511;
        wih2[e] = packh2(wih[h * I_ + (i2 << 1)], wih[h * I_ + (i2 << 1) + 1]);
    }
    if (e < H_) biasv[e] = bih[e] + bhh[e];
}

// ---------------- xp = x @ W_ih^T + biases, fp16 [B][T][H] (unchanged) --------
__global__ __launch_bounds__(512, 2) void xp_gemm(
    const float* __restrict__ x, const unsigned* __restrict__ wih2,
    const float* __restrict__ biasv, _Float16* __restrict__ xph) {
    __shared__ unsigned w2[64 * 512];
    __shared__ unsigned x2[32 * 64];
    const int tid = threadIdx.x, b = blockIdx.x, t0 = blockIdx.y * 32;

    #pragma unroll
    for (int q = 0; q < 64; ++q) w2[tid + (q << 9)] = wih2[tid + (q << 9)];
    #pragma unroll
    for (int q = 0; q < 4; ++q) {
        int idx = tid * 4 + q;
        int t = idx >> 6, i2 = idx & 63;
        const float2 xv = *(const float2*)(x + ((size_t)b * T_ + t0 + t) * I_ + (i2 << 1));
        x2[idx] = packh2(xv.x, xv.y);
    }
    __syncthreads();
    const float bias = biasv[tid];
    for (int t = 0; t < 32; ++t) {
        float acc = bias;
        #pragma unroll
        for (int i2 = 0; i2 < 64; ++i2)
            acc = fdot2u(x2[(t << 6) + i2], w2[(i2 << 9) + tid], acc);
        xph[((size_t)b * T_ + t0 + t) * H_ + tid] = (_Float16)acc;
    }
}

// ---------------- serial recurrence: TWO WGs per chain, flag sync via L2 ------
// wg = chain | (half<<6); partner = wg ^ 64 (same XCD under round-robin).
// Each WG computes 256 rows; h halves exchanged through hglob (global, L2).
__global__ __launch_bounds__(512) void rnn_fused(
    const unsigned* __restrict__ xp2,    // [B][T][256] half2 words
    const unsigned* __restrict__ wpack,
    const unsigned* __restrict__ wldsg,
    const float* __restrict__ fcw, const float* __restrict__ fcb,
    unsigned* __restrict__ hglob,        // [B][2][256] h2 words (zeroed)
    int* __restrict__ flags,             // [B][2] step counters (zeroed)
    float* __restrict__ out)
{
    __shared__ __align__(16) unsigned wlds[16384];   // 64 KB LDS weight part
    __shared__ float wsum[8];

    const int tid = threadIdx.x;
    const int wg = blockIdx.x;
    const int b = wg & 63;
    const int half = wg >> 6;
    const int w = tid >> 6, l = tid & 63, c = l & 3, u = l >> 2;
    const int g = w * 16 + u;

    {   // stage LDS weights: 4096 uint4, 8 each, coalesced ([m][tid] layout)
        const uint4* src = ((const uint4*)wldsg) + half * 4096;
        uint4* dst = (uint4*)wlds;
        #pragma unroll
        for (int q = 0; q < 8; ++q) dst[tid + (q << 9)] = src[tid + (q << 9)];
    }
    uint4 wrA[2][8], wrB[8];             // 96 VGPRs of packed half2 weights
    {
        const uint4* wp4 = ((const uint4*)wpack) + half * 12288 + tid;
        #pragma unroll
        for (int r = 0; r < 2; ++r)
            #pragma unroll
            for (int q = 0; q < 8; ++q) wrA[r][q] = wp4[((r << 3) + q) << 9];
        #pragma unroll
        for (int q = 0; q < 8; ++q) wrB[q] = wp4[(16 + q) << 9];
    }
    __syncthreads();

    const unsigned* xpb = xp2 + (size_t)b * T_ * 256 + half * 128 + g;
    const uint4* hb4 = ((const uint4*)hglob) + (b << 7);      // + parity*64
    unsigned* hst = hglob + (b << 9) + (half << 7) + g;       // + parity*256
    const uint4* wl4 = ((const uint4*)wlds) + tid;
    const int mf = (b << 1) | half;
    const int pf = (b << 1) | (half ^ 1);

    unsigned xpw = xpb[0];

    for (int t = 0; t < T_; ++t) {
        // wait for partner's h(t) (t=0 passes: flags start at 0)
        while (__hip_atomic_load(&flags[pf], __ATOMIC_RELAXED,
                                 __HIP_MEMORY_SCOPE_AGENT) < t)
            __builtin_amdgcn_s_sleep(1);
        __builtin_amdgcn_fence(__ATOMIC_ACQUIRE, "agent");   // inv L1

        const uint4* hp = hb4 + ((t & 1) << 6);
        uint4 hc[8], hd[8];
        #pragma unroll
        for (int q = 0; q < 8; ++q) hc[q] = hp[(c << 3) + q];        // chunk c
        #pragma unroll
        for (int q = 0; q < 8; ++q) hd[q] = hp[((c + 4) << 3) + q];  // chunk c+4
        unsigned xpn = (t + 1 < T_) ? xpb[(t + 1) * 256] : 0u;

        float a0 = 0.f, a1 = 0.f;
        #pragma unroll
        for (int q = 0; q < 8; ++q) {
            const uint4 hh = hc[q];
            a0 = fdot2u(wrA[0][q].x, hh.x, a0); a1 = fdot2u(wrA[1][q].x, hh.x, a1);
            a0 = fdot2u(wrA[0][q].y, hh.y, a0); a1 = fdot2u(wrA[1][q].y, hh.y, a1);
            a0 = fdot2u(wrA[0][q].z, hh.z, a0); a1 = fdot2u(wrA[1][q].z, hh.z, a1);
            a0 = fdot2u(wrA[0][q].w, hh.w, a0); a1 = fdot2u(wrA[1][q].w, hh.w, a1);
        }
        #pragma unroll
        for (int q = 0; q < 8; ++q) {
            const uint4 hh = hd[q];
            const uint4 wb = wrB[q];
            const uint4 wl = wl4[q << 9];        // coalesced b128, imm offset
            a0 = fdot2u(wb.x, hh.x, a0); a1 = fdot2u(wl.x, hh.x, a1);
            a0 = fdot2u(wb.y, hh.y, a0); a1 = fdot2u(wl.y, hh.y, a1);
            a0 = fdot2u(wb.z, hh.z, a0); a1 = fdot2u(wl.z, hh.z, a1);
            a0 = fdot2u(wb.w, hh.w, a0); a1 = fdot2u(wl.w, hh.w, a1);
        }
        // reduce over k-slices (lane bits 0,1) — DPP quad-perm adds
        a0 += __shfl_xor(a0, 1); a0 += __shfl_xor(a0, 2);
        a1 += __shfl_xor(a1, 1); a1 += __shfl_xor(a1, 2);

        U32H2 xu; xu.u = xpw;
        const float p0 = (float)xu.h.x + a0;
        const float p1 = (float)xu.h.y + a1;
        const float e0 = __expf(2.f * p0), e1 = __expf(2.f * p1);
        const float h0 = 1.f - 2.f / (e0 + 1.f);
        const float h1 = 1.f - 2.f / (e1 + 1.f);
        if (c == 0) hst[(((t + 1) & 1) << 8)] = packh2(h0, h1);  // 64B/wave
        xpw = xpn;
        __syncthreads();                 // drains stores (vmcnt 0) + syncs WG
        if (tid == 0)
            __hip_atomic_store(&flags[mf], t + 1, __ATOMIC_RELEASE,
                               __HIP_MEMORY_SCOPE_AGENT);
    }

    // head: half 0 gathers both halves of h(T) (parity 0) and writes out[b]
    if (half == 0) {
        while (__hip_atomic_load(&flags[pf], __ATOMIC_RELAXED,
                                 __HIP_MEMORY_SCOPE_AGENT) < T_)
            __builtin_amdgcn_s_sleep(1);
        __builtin_amdgcn_fence(__ATOMIC_ACQUIRE, "agent");
        float pr = 0.f;
        if (tid < 256) {
            U32H2 hu; hu.u = hglob[(b << 9) + tid];
            pr = (float)hu.h.x * fcw[tid << 1] + (float)hu.h.y * fcw[(tid << 1) + 1];
        }
        #pragma unroll
        for (int off = 32; off >= 1; off >>= 1) pr += __shfl_down(pr, off, 64);
        if ((tid & 63) == 0 && tid < 256) wsum[tid >> 6] = pr;
        __syncthreads();
        if (tid == 0) out[b] = wsum[0] + wsum[1] + wsum[2] + wsum[3] + fcb[0];
    }
}

extern "C" void kernel_launch(void* const* d_in, const int* in_sizes, int n_in,
                              void* d_out, int out_size, void* d_ws, size_t ws_size,
                              hipStream_t stream) {
    const float* x   = (const float*)d_in[0];
    const float* wih = (const float*)d_in[1];
    const float* whh = (const float*)d_in[2];
    const float* bih = (const float*)d_in[3];
    const float* bhh = (const float*)d_in[4];
    const float* fcw = (const float*)d_in[5];
    const float* fcb = (const float*)d_in[6];
    float* out = (float*)d_out;

    // workspace (u32 units), same footprint as R2 (proven to fit):
    // xp2 | wpack | wldsg | wih2 | biasv ; hglob/flags OVERLAY wih2/biasv
    // (wih2+biasv are dead after xp_gemm; memset between xp_gemm and rnn).
    unsigned* xp2   = (unsigned*)d_ws;            // 16,777,216
    unsigned* wpack = xp2 + 16777216;             // 98,304
    unsigned* wldsg = wpack + 98304;              // 32,768
    unsigned* wih2  = wldsg + 32768;              // 32,768
    float*    biasv = (float*)(wih2 + 32768);     // 512
    unsigned* hglob = wih2;                       // 32,768 u32 (B*2*256)
    int*      flags = (int*)biasv;                // 128 ints

    hipLaunchKernelGGL(prep, dim3(384), dim3(256), 0, stream,
                       wih, whh, bih, bhh, wpack, wldsg, wih2, biasv);
    hipLaunchKernelGGL(xp_gemm, dim3(B_, 32), dim3(512), 0, stream,
                       x, wih2, biasv, (_Float16*)xp2);
    hipMemsetAsync(hglob, 0, 32768 * 4 + 512, stream);   // h(0)=0, flags=0
    hipLaunchKernelGGL(rnn_fused, dim3(128), dim3(512), 0, stream,
                       xp2, wpack, wldsg, fcw, fcb, hglob, flags, out);
}

// Round 9
// 2612.544 us; speedup vs baseline: 3.7857x; 3.7857x over previous
//
#include <hip/hip_runtime.h>
#include <math.h>

#define B_ 64
#define T_ 1024
#define I_ 128
#define H_ 512

typedef _Float16 h2_t __attribute__((ext_vector_type(2)));
union U32H2 { unsigned u; h2_t h; };

__device__ __forceinline__ float fdot2u(unsigned a, unsigned b, float c) {
    U32H2 ua, ub; ua.u = a; ub.u = b;
    return __builtin_amdgcn_fdot2(ua.h, ub.h, c, false);
}
__device__ __forceinline__ unsigned packh2(float x, float y) {
    U32H2 r; r.h.x = (_Float16)x; r.h.y = (_Float16)y; return r.u;
}

// ---------------- prep: pack ALL of W_hh into per-thread register layout ------
// rnn map: c=tid>>7 (k-slice: h2-words 64c..64c+63), g=tid&127 (rows 4g..4g+3).
// wpack uint4[slot*512 + tid], slot=j*16+q (j=0..3 row, q=0..15 word-quad):
//   component r4 = half2 W[4g+j][2*(64c+4q+r4) .. +1]
// wih2[(i2<<9)+h] = half2 Wih[h][2i2..+1];  biasv[h] = b_ih[h]+b_hh[h]
__global__ void prep(const float* __restrict__ wih, const float* __restrict__ whh,
                     const float* __restrict__ bih, const float* __restrict__ bhh,
                     unsigned* __restrict__ wpack,
                     unsigned* __restrict__ wih2, float* __restrict__ biasv) {
    int e = blockIdx.x * 256 + threadIdx.x;
    if (e < 131072) {                    // 64 slots * 512 tid * 4 comp
        int r4 = e & 3;
        int u4 = e >> 2;                 // uint4 index
        int slot = u4 >> 9, tid = u4 & 511;
        int j = slot >> 4, q = slot & 15;
        int c = tid >> 7, g = tid & 127;
        int row = (g << 2) + j;
        int word = (c << 6) + (q << 2) + r4;
        wpack[e] = packh2(whh[row * H_ + 2 * word], whh[row * H_ + 2 * word + 1]);
    }
    if (e < 64 * 512) {
        int i2 = e >> 9, h = e & 511;
        wih2[e] = packh2(wih[h * I_ + (i2 << 1)], wih[h * I_ + (i2 << 1) + 1]);
    }
    if (e < H_) biasv[e] = bih[e] + bhh[e];
}

// ---------------- xp = x @ W_ih^T + biases, fp16 [B][T][H] (unchanged) --------
__global__ __launch_bounds__(512, 2) void xp_gemm(
    const float* __restrict__ x, const unsigned* __restrict__ wih2,
    const float* __restrict__ biasv, _Float16* __restrict__ xph) {
    __shared__ unsigned w2[64 * 512];
    __shared__ unsigned x2[32 * 64];
    const int tid = threadIdx.x, b = blockIdx.x, t0 = blockIdx.y * 32;

    #pragma unroll
    for (int q = 0; q < 64; ++q) w2[tid + (q << 9)] = wih2[tid + (q << 9)];
    #pragma unroll
    for (int q = 0; q < 4; ++q) {
        int idx = tid * 4 + q;
        int t = idx >> 6, i2 = idx & 63;
        const float2 xv = *(const float2*)(x + ((size_t)b * T_ + t0 + t) * I_ + (i2 << 1));
        x2[idx] = packh2(xv.x, xv.y);
    }
    __syncthreads();
    const float bias = biasv[tid];
    for (int t = 0; t < 32; ++t) {
        float acc = bias;
        #pragma unroll
        for (int i2 = 0; i2 < 64; ++i2)
            acc = fdot2u(x2[(t << 6) + i2], w2[(i2 << 9) + tid], acc);
        xph[((size_t)b * T_ + t0 + t) * H_ + tid] = (_Float16)acc;
    }
}

// ---------------- serial recurrence: one WG per chain, ZERO LDS weights -------
// All 256 weight h2-words per thread live in the unified VGPR/AGPR file
// (8 waves x 256 regs = the full 512 KB file). DS per step = h reads + tail.
__global__ __launch_bounds__(512) void rnn_fused(
    const unsigned* __restrict__ xp2,    // [B][T][256] half2 words
    const unsigned* __restrict__ wpack,  // [64 slots][512 tid] uint4
    const float* __restrict__ fcw, const float* __restrict__ fcb,
    float* __restrict__ out)
{
    __shared__ __align__(16) float part[4 * 512];    // 8 KB partials
    __shared__ __align__(16) unsigned h2buf[256];    // 1 KB h (half2)
    __shared__ float wsum[4];

    const int tid = threadIdx.x;
    const int b = blockIdx.x;
    const int c = tid >> 7, g = tid & 127;

    // full weight residency: 64 uint4 = 256 u32 words per thread
    uint4 wr0[16], wr1[16], wr2[16], wr3[16];
    {
        const uint4* wp4 = ((const uint4*)wpack) + tid;
        #pragma unroll
        for (int q = 0; q < 16; ++q) wr0[q] = wp4[(0 * 16 + q) << 9];
        #pragma unroll
        for (int q = 0; q < 16; ++q) wr1[q] = wp4[(1 * 16 + q) << 9];
        #pragma unroll
        for (int q = 0; q < 16; ++q) wr2[q] = wp4[(2 * 16 + q) << 9];
        #pragma unroll
        for (int q = 0; q < 16; ++q) wr3[q] = wp4[(3 * 16 + q) << 9];
    }
    if (tid < 256) h2buf[tid] = 0u;
    __syncthreads();

    const unsigned* xpb = xp2 + (size_t)b * T_ * 256;
    const uint4* hv = ((const uint4*)h2buf) + (c << 4);   // wave-uniform base
    float4* part4w = ((float4*)part) + (c << 7) + g;
    const float2* p2 = (const float2*)part;

    unsigned xpw = (tid < 256) ? xpb[tid] : 0u;           // xp[0]

    for (int t = 0; t < T_; ++t) {
        // prefetch xp[t+1] (t=1023 reads into wpack region: valid, unused)
        unsigned xpn = (tid < 256) ? xpb[(t + 1) * 256 + tid] : 0u;

        float a0 = 0.f, a1 = 0.f, a2 = 0.f, a3 = 0.f;
        #pragma unroll
        for (int q = 0; q < 16; ++q) {
            const uint4 hh = hv[q];      // uniform b128 from LDS
            a0 = fdot2u(wr0[q].x, hh.x, a0); a1 = fdot2u(wr1[q].x, hh.x, a1);
            a2 = fdot2u(wr2[q].x, hh.x, a2); a3 = fdot2u(wr3[q].x, hh.x, a3);
            a0 = fdot2u(wr0[q].y, hh.y, a0); a1 = fdot2u(wr1[q].y, hh.y, a1);
            a2 = fdot2u(wr2[q].y, hh.y, a2); a3 = fdot2u(wr3[q].y, hh.y, a3);
            a0 = fdot2u(wr0[q].z, hh.z, a0); a1 = fdot2u(wr1[q].z, hh.z, a1);
            a2 = fdot2u(wr2[q].z, hh.z, a2); a3 = fdot2u(wr3[q].z, hh.z, a3);
            a0 = fdot2u(wr0[q].w, hh.w, a0); a1 = fdot2u(wr1[q].w, hh.w, a1);
            a2 = fdot2u(wr2[q].w, hh.w, a2); a3 = fdot2u(wr3[q].w, hh.w, a3);
        }
        *part4w = make_float4(a0, a1, a2, a3);
        __syncthreads();                 // partials ready

        if (tid < 256) {                 // 4 waves: cross-chunk reduce + tanh
            float2 s0 = p2[tid];
            float2 s1 = p2[256 + tid];
            float2 s2 = p2[512 + tid];
            float2 s3 = p2[768 + tid];
            U32H2 xu; xu.u = xpw;
            float pre0 = (float)xu.h.x + s0.x + s1.x + s2.x + s3.x;
            float pre1 = (float)xu.h.y + s0.y + s1.y + s2.y + s3.y;
            float e0 = __expf(2.0f * pre0), e1 = __expf(2.0f * pre1);
            float h0 = 1.0f - 2.0f / (e0 + 1.0f);
            float h1 = 1.0f - 2.0f / (e1 + 1.0f);
            h2buf[tid] = packh2(h0, h1);
        }
        xpw = xpn;
        __syncthreads();                 // h ready
    }

    // head: out[b] = dot(h, fc_w) + fc_b
    float p = 0.f;
    if (tid < 256) {
        U32H2 hu; hu.u = h2buf[tid];
        p = (float)hu.h.x * fcw[tid << 1] + (float)hu.h.y * fcw[(tid << 1) + 1];
    }
    #pragma unroll
    for (int off = 32; off >= 1; off >>= 1) p += __shfl_down(p, off, 64);
    if ((tid & 63) == 0 && tid < 256) wsum[tid >> 6] = p;
    __syncthreads();
    if (tid == 0) out[b] = wsum[0] + wsum[1] + wsum[2] + wsum[3] + fcb[0];
}

extern "C" void kernel_launch(void* const* d_in, const int* in_sizes, int n_in,
                              void* d_out, int out_size, void* d_ws, size_t ws_size,
                              hipStream_t stream) {
    const float* x   = (const float*)d_in[0];
    const float* wih = (const float*)d_in[1];
    const float* whh = (const float*)d_in[2];
    const float* bih = (const float*)d_in[3];
    const float* bhh = (const float*)d_in[4];
    const float* fcw = (const float*)d_in[5];
    const float* fcb = (const float*)d_in[6];
    float* out = (float*)d_out;

    // workspace (u32 units): xp2 | wpack | wih2 | biasv  (~64.6 MiB, same as R2)
    unsigned* xp2   = (unsigned*)d_ws;            // 16,777,216
    unsigned* wpack = xp2 + 16777216;             // 131,072
    unsigned* wih2  = wpack + 131072;             // 32,768
    float*    biasv = (float*)(wih2 + 32768);     // 512

    hipLaunchKernelGGL(prep, dim3(512), dim3(256), 0, stream,
                       wih, whh, bih, bhh, wpack, wih2, biasv);
    hipLaunchKernelGGL(xp_gemm, dim3(B_, 32), dim3(512), 0, stream,
                       x, wih2, biasv, (_Float16*)xp2);
    hipLaunchKernelGGL(rnn_fused, dim3(B_), dim3(512), 0, stream,
                       xp2, wpack, fcw, fcb, out);
}

// Round 10
// 1733.367 us; speedup vs baseline: 5.7058x; 1.5072x over previous
//
#include <hip/hip_runtime.h>
#include <math.h>

#define B_ 64
#define T_ 1024
#define I_ 128
#define H_ 512

typedef _Float16 h2_t __attribute__((ext_vector_type(2)));
union U32H2 { unsigned u; h2_t h; };

__device__ __forceinline__ float fdot2u(unsigned a, unsigned b, float c) {
    U32H2 ua, ub; ua.u = a; ub.u = b;
    return __builtin_amdgcn_fdot2(ua.h, ub.h, c, false);
}
__device__ __forceinline__ unsigned packh2(float x, float y) {
    U32H2 r; r.h.x = (_Float16)x; r.h.y = (_Float16)y; return r.u;
}
__device__ __forceinline__ int sdot4(unsigned a, unsigned b, int c) {
    return __builtin_amdgcn_sdot4((int)a, (int)b, c, false);
}

// ---------------- prep_w: int8-quantize W_hh with per-row scale ---------------
// rnn map (512 thr): c=tid>>6 (k-slice: bytes 64c..64c+63), g=tid&63
// (rows 8g..8g+7). wpackq uint4[(r*4+q)*512 + tid] = 16 int8 of row 8g+r,
// k-bytes 64c+16q .. +15.  wsbuf[j] = rowmax_j/127.
__global__ __launch_bounds__(64) void prep_w(const float* __restrict__ whh,
                                             unsigned* __restrict__ wpackq,
                                             float* __restrict__ wsbuf) {
    const int j = blockIdx.x;            // output row
    const int l = threadIdx.x;           // lane: k-bytes 8l..8l+7
    float v[8]; float m = 0.f;
    #pragma unroll
    for (int i = 0; i < 8; ++i) {
        v[i] = whh[j * H_ + l * 8 + i];
        m = fmaxf(m, fabsf(v[i]));
    }
    #pragma unroll
    for (int off = 32; off >= 1; off >>= 1) m = fmaxf(m, __shfl_xor(m, off, 64));
    const float rs = (m > 0.f) ? 127.f / m : 0.f;
    if (l == 0) wsbuf[j] = (m > 0.f) ? m / 127.f : 0.f;
    unsigned pk0 = 0u, pk1 = 0u;
    #pragma unroll
    for (int i = 0; i < 8; ++i) {
        int q = (int)rintf(v[i] * rs);
        q = max(-127, min(127, q));
        if (i < 4) pk0 |= ((unsigned)(q & 255)) << (i * 8);
        else       pk1 |= ((unsigned)(q & 255)) << ((i - 4) * 8);
    }
    const int g = (j >> 3) & 63, r = j & 7;
    const int c = l >> 3, q4 = (l >> 1) & 3, dw = (l & 1) * 2;
    const int idx = (((r * 4 + q4) * 512) + c * 64 + g) * 4 + dw;
    wpackq[idx]     = pk0;
    wpackq[idx + 1] = pk1;
}

// ---------------- prep_misc: W_ih fp16 pack + combined bias -------------------
__global__ void prep_misc(const float* __restrict__ wih,
                          const float* __restrict__ bih, const float* __restrict__ bhh,
                          unsigned* __restrict__ wih2, float* __restrict__ biasv) {
    int e = blockIdx.x * 256 + threadIdx.x;
    if (e < 64 * 512) {
        int i2 = e >> 9, h = e & 511;
        wih2[e] = packh2(wih[h * I_ + (i2 << 1)], wih[h * I_ + (i2 << 1) + 1]);
    }
    if (e < H_) biasv[e] = bih[e] + bhh[e];
}

// ---------------- xp = x @ W_ih^T + biases, fp16 [B][T][H] (proven) -----------
__global__ __launch_bounds__(512, 2) void xp_gemm(
    const float* __restrict__ x, const unsigned* __restrict__ wih2,
    const float* __restrict__ biasv, _Float16* __restrict__ xph) {
    __shared__ unsigned w2[64 * 512];
    __shared__ unsigned x2[32 * 64];
    const int tid = threadIdx.x, b = blockIdx.x, t0 = blockIdx.y * 32;

    #pragma unroll
    for (int q = 0; q < 64; ++q) w2[tid + (q << 9)] = wih2[tid + (q << 9)];
    #pragma unroll
    for (int q = 0; q < 4; ++q) {
        int idx = tid * 4 + q;
        int t = idx >> 6, i2 = idx & 63;
        const float2 xv = *(const float2*)(x + ((size_t)b * T_ + t0 + t) * I_ + (i2 << 1));
        x2[idx] = packh2(xv.x, xv.y);
    }
    __syncthreads();
    const float bias = biasv[tid];
    for (int t = 0; t < 32; ++t) {
        float acc = bias;
        #pragma unroll
        for (int i2 = 0; i2 < 64; ++i2)
            acc = fdot2u(x2[(t << 6) + i2], w2[(i2 << 9) + tid], acc);
        xph[((size_t)b * T_ + t0 + t) * H_ + tid] = (_Float16)acc;
    }
}

// ---------------- serial recurrence: int8 dual-dot, ZERO LDS weights ----------
// 512 thr: c=tid>>6 (k-slice), g=tid&63 (rows 8g..8g+7). Weights: 32 uint4
// int8 in VGPRs. h: dual int8 (hi + residual lo) in 1 KB LDS. Per step:
// 8 uniform b128 h-reads, 256 sdot4, 2 part-writes, 2 barriers.
__global__ __launch_bounds__(512) void rnn_fused(
    const unsigned* __restrict__ xp2,    // [B][T][256] half2 words
    const unsigned* __restrict__ wpackq, // [32 slots][512 tid] uint4 int8
    const float* __restrict__ wsbuf,     // [512] per-row scales
    const float* __restrict__ fcw, const float* __restrict__ fcb,
    float* __restrict__ out)
{
    __shared__ __align__(16) float part[8 * 2 * 64 * 4];  // 16 KB [c][h2][g][4]
    __shared__ __align__(16) unsigned hq[256];            // hi[128] | lo[128]
    __shared__ float wsum[2];

    const int tid = threadIdx.x;
    const int b = blockIdx.x;
    const int c = tid >> 6, g = tid & 63;

    uint4 wq[8][4];                      // 128 VGPRs of int8 weights
    {
        const uint4* wp4 = ((const uint4*)wpackq) + tid;
        #pragma unroll
        for (int r = 0; r < 8; ++r)
            #pragma unroll
            for (int q = 0; q < 4; ++q)
                wq[r][q] = wp4[(r * 4 + q) << 9];
    }
    float4 wsv = make_float4(0.f, 0.f, 0.f, 0.f);
    if (tid < 128) wsv = ((const float4*)wsbuf)[tid];     // rows 4tid..4tid+3
    if (tid < 256) hq[tid] = 0u;                          // h(0) = 0
    __syncthreads();

    const unsigned* xpb = xp2 + (size_t)b * T_ * 256;
    const uint4* hhi4 = ((const uint4*)hq) + (c << 2);          // uniform base
    const uint4* hlo4 = ((const uint4*)(hq + 128)) + (c << 2);
    float4* pwf = ((float4*)part) + (c << 7) + g;
    const float4* prd = ((const float4*)part) + ((tid & 1) << 6) + (tid >> 1);

    uint2 xpw = make_uint2(0u, 0u);
    if (tid < 128) xpw = *(const uint2*)(xpb + 2 * tid);        // xp[0]

    for (int t = 0; t < T_; ++t) {
        uint2 xpn = make_uint2(0u, 0u);   // prefetch (t=1023 reads wpackq: ok)
        if (tid < 128) xpn = *(const uint2*)(xpb + (t + 1) * 256 + 2 * tid);

        int ah[8] = {0,0,0,0,0,0,0,0};
        int al[8] = {0,0,0,0,0,0,0,0};
        #pragma unroll
        for (int q = 0; q < 4; ++q) {
            const uint4 hh = hhi4[q];     // uniform b128 broadcast
            const uint4 hl = hlo4[q];
            #pragma unroll
            for (int r = 0; r < 8; ++r) {
                const uint4 w = wq[r][q];
                ah[r] = sdot4(w.x, hh.x, ah[r]); ah[r] = sdot4(w.y, hh.y, ah[r]);
                ah[r] = sdot4(w.z, hh.z, ah[r]); ah[r] = sdot4(w.w, hh.w, ah[r]);
                al[r] = sdot4(w.x, hl.x, al[r]); al[r] = sdot4(w.y, hl.y, al[r]);
                al[r] = sdot4(w.z, hl.z, al[r]); al[r] = sdot4(w.w, hl.w, al[r]);
            }
        }
        float pf[8];
        #pragma unroll
        for (int r = 0; r < 8; ++r)
            pf[r] = (float)ah[r] * (1.f / 127.f) + (float)al[r] * (1.f / 16129.f);
        pwf[0]  = make_float4(pf[0], pf[1], pf[2], pf[3]);   // rows 8g..8g+3
        pwf[64] = make_float4(pf[4], pf[5], pf[6], pf[7]);   // rows 8g+4..8g+7
        __syncthreads();                  // partials ready

        if (tid < 128) {                  // outputs 4tid..4tid+3
            float4 s = prd[0];
            #pragma unroll
            for (int cc = 1; cc < 8; ++cc) {
                const float4 v = prd[cc << 7];
                s.x += v.x; s.y += v.y; s.z += v.z; s.w += v.w;
            }
            U32H2 xa, xb; xa.u = xpw.x; xb.u = xpw.y;
            const float pre0 = (float)xa.h.x + wsv.x * s.x;
            const float pre1 = (float)xa.h.y + wsv.y * s.y;
            const float pre2 = (float)xb.h.x + wsv.z * s.z;
            const float pre3 = (float)xb.h.y + wsv.w * s.w;
            const float h0 = 1.f - 2.f / (__expf(2.f * pre0) + 1.f);
            const float h1 = 1.f - 2.f / (__expf(2.f * pre1) + 1.f);
            const float h2 = 1.f - 2.f / (__expf(2.f * pre2) + 1.f);
            const float h3 = 1.f - 2.f / (__expf(2.f * pre3) + 1.f);
            const int q0 = (int)rintf(h0 * 127.f);
            const int q1 = (int)rintf(h1 * 127.f);
            const int q2 = (int)rintf(h2 * 127.f);
            const int q3 = (int)rintf(h3 * 127.f);
            const int e0 = (int)rintf((h0 - (float)q0 * (1.f / 127.f)) * 16129.f);
            const int e1 = (int)rintf((h1 - (float)q1 * (1.f / 127.f)) * 16129.f);
            const int e2 = (int)rintf((h2 - (float)q2 * (1.f / 127.f)) * 16129.f);
            const int e3 = (int)rintf((h3 - (float)q3 * (1.f / 127.f)) * 16129.f);
            hq[tid]       = (unsigned)(q0 & 255) | ((unsigned)(q1 & 255) << 8) |
                            ((unsigned)(q2 & 255) << 16) | ((unsigned)(q3 & 255) << 24);
            hq[128 + tid] = (unsigned)(e0 & 255) | ((unsigned)(e1 & 255) << 8) |
                            ((unsigned)(e2 & 255) << 16) | ((unsigned)(e3 & 255) << 24);
        }
        xpw = xpn;
        __syncthreads();                  // h(t+1) ready
    }

    // head: out[b] = dot(h, fc_w) + fc_b   (h reconstructed from dual int8)
    float p = 0.f;
    if (tid < 128) {
        const unsigned uhi = hq[tid], ulo = hq[128 + tid];
        const float4 fw = ((const float4*)fcw)[tid];
        const float h0 = (float)(int)(signed char)(uhi & 255u)        * (1.f/127.f)
                       + (float)(int)(signed char)(ulo & 255u)        * (1.f/16129.f);
        const float h1 = (float)(int)(signed char)((uhi >> 8) & 255u) * (1.f/127.f)
                       + (float)(int)(signed char)((ulo >> 8) & 255u) * (1.f/16129.f);
        const float h2 = (float)(int)(signed char)((uhi >> 16) & 255u)* (1.f/127.f)
                       + (float)(int)(signed char)((ulo >> 16) & 255u)* (1.f/16129.f);
        const float h3 = (float)(int)(signed char)(uhi >> 24)         * (1.f/127.f)
                       + (float)(int)(signed char)(ulo >> 24)         * (1.f/16129.f);
        p = h0 * fw.x + h1 * fw.y + h2 * fw.z + h3 * fw.w;
    }
    #pragma unroll
    for (int off = 32; off >= 1; off >>= 1) p += __shfl_down(p, off, 64);
    if ((tid & 63) == 0 && tid < 128) wsum[tid >> 6] = p;
    __syncthreads();
    if (tid == 0) out[b] = wsum[0] + wsum[1] + fcb[0];
}

extern "C" void kernel_launch(void* const* d_in, const int* in_sizes, int n_in,
                              void* d_out, int out_size, void* d_ws, size_t ws_size,
                              hipStream_t stream) {
    const float* x   = (const float*)d_in[0];
    const float* wih = (const float*)d_in[1];
    const float* whh = (const float*)d_in[2];
    const float* bih = (const float*)d_in[3];
    const float* bhh = (const float*)d_in[4];
    const float* fcw = (const float*)d_in[5];
    const float* fcb = (const float*)d_in[6];
    float* out = (float*)d_out;

    // workspace (u32 units): xp2 | wpackq | wih2 | biasv | wsbuf  (~64.4 MiB)
    unsigned* xp2    = (unsigned*)d_ws;           // 16,777,216
    unsigned* wpackq = xp2 + 16777216;            // 65,536
    unsigned* wih2   = wpackq + 65536;            // 32,768
    float*    biasv  = (float*)(wih2 + 32768);    // 512
    float*    wsbuf  = biasv + 512;               // 512

    hipLaunchKernelGGL(prep_w, dim3(512), dim3(64), 0, stream,
                       whh, wpackq, wsbuf);
    hipLaunchKernelGGL(prep_misc, dim3(128), dim3(256), 0, stream,
                       wih, bih, bhh, wih2, biasv);
    hipLaunchKernelGGL(xp_gemm, dim3(B_, 32), dim3(512), 0, stream,
                       x, wih2, biasv, (_Float16*)xp2);
    hipLaunchKernelGGL(rnn_fused, dim3(B_), dim3(512), 0, stream,
                       xp2, wpackq, wsbuf, fcw, fcb, out);
}